// Round 9
// baseline (255.910 us; speedup 1.0000x reference)
//
#include <hip/hip_runtime.h>
#include <float.h>

typedef int i32x16 __attribute__((ext_vector_type(16)));

#define NTOK   65536
#define DIM    256
#define NCODE  1024
#define TT     64         // tokens per block; grid = 1024
#define CAP    4096
#define SX     20.0f      // x quant scale (clamp at 6.35 sigma)
#define SW     360.0f     // w quant scale (w sigma = 1/16, clamp 5.6 sigma)
#define TAU_I  1260       // 0.35 * SX*SW/2 (int-domain tau; passed R6/R7 at 16-code groups)
#define BIAS_I 230400     // 64 * SX*SW/2  (keeps int coarse score strictly positive)

__device__ inline unsigned q4(float4 v, float s) {
    int q0 = (int)rintf(fminf(fmaxf(v.x * s, -127.f), 127.f));
    int q1 = (int)rintf(fminf(fmaxf(v.y * s, -127.f), 127.f));
    int q2 = (int)rintf(fminf(fmaxf(v.z * s, -127.f), 127.f));
    int q3 = (int)rintf(fminf(fmaxf(v.w * s, -127.f), 127.f));
    return (unsigned)(q0 & 255) | ((unsigned)(q1 & 255) << 8) |
           ((unsigned)(q2 & 255) << 16) | ((unsigned)(q3 & 255) << 24);
}
__device__ inline long pk8(float4 a, float4 b, float s) {
    union { unsigned u[2]; long l; } r;
    r.u[0] = q4(a, s); r.u[1] = q4(b, s);
    return r.l;
}
__device__ inline unsigned umn(unsigned a, unsigned b) { return a < b ? a : b; }
__device__ inline unsigned umx(unsigned a, unsigned b) { return a > b ? a : b; }

// pre-kernel (R7-verified): ||W_k||^2 fp64->fp32 + W -> i8 K-MAJOR tiles:
// wq[ct*2048 + g*64 + r] = granule g (8 dims) of code row r in 64-code tile ct.
__global__ __launch_bounds__(256) void prep_kernel(const float* __restrict__ W,
                                                   float* __restrict__ nw_out,
                                                   long* __restrict__ wq_out) {
    const int tid = threadIdx.x;
    const int k = blockIdx.x * 8 + (tid >> 5);
    const int c = tid & 31;
    const float4* wr = (const float4*)(W + (size_t)k * DIM + c * 8);
    float4 u = wr[0], v = wr[1];
    wq_out[(size_t)(k >> 6) * 2048 + (size_t)c * 64 + (k & 63)] = pk8(u, v, SW);
    double a = (double)u.x * u.x + (double)u.y * u.y + (double)u.z * u.z + (double)u.w * u.w
             + (double)v.x * v.x + (double)v.y * v.y + (double)v.z * v.z + (double)v.w * v.w;
    #pragma unroll
    for (int m = 1; m <= 16; m <<= 1) a += __shfl_xor(a, m);
    if (c == 0) nw_out[k] = (float)a;
}

// (256,3): 170-reg budget >> ~145 true pressure -> no squeeze-spill (R1/R3 failure
// mode at 128-budget) and no pad-to-256 2-block cap (R4/R7 failure mode).
template <bool PRE>
__global__ __launch_bounds__(256, 3)
void vq_kernel(
    const float* __restrict__ x, const float* __restrict__ W,
    const float* __restrict__ nwp, const long* __restrict__ wqp,
    float* __restrict__ outq, float* __restrict__ outidx)
{
    __shared__ __align__(16) char ttile[16384];   // TOKEN tile, K-major: byte = g*512 + t*8
    __shared__ float nw_s[NCODE];                 // fp32 norms (exact rescore)
    __shared__ int   nwb_s[NCODE];                // BIAS_I + rint(nw * SX*SW/2)
    __shared__ float nx_s[TT];
    __shared__ unsigned tmin_s[TT];
    __shared__ unsigned long long best64[TT];
    __shared__ int cnt_s;
    __shared__ int bk_s[TT];
    unsigned* cand = (unsigned*)ttile;            // aliased after coarse phase

    const int tid = threadIdx.x, tb = blockIdx.x * TT;
    const int wv = tid >> 6, l = tid & 63;
    const int ln = l & 31, h = l >> 5;

    // ---- nw: precomputed or fp64 in-block fallback ----
    if (PRE) {
        ((float4*)nw_s)[tid] = ((const float4*)nwp)[tid];
    } else {
        #pragma unroll
        for (int c = 0; c < 4; ++c) {
            const int k = (tid << 2) + c;
            const float4* wr = (const float4*)(W + (size_t)k * DIM);
            double a0 = 0.0, a1 = 0.0;
            for (int q = 0; q < DIM / 4; ++q) {
                float4 v = wr[q];
                a0 += (double)v.x * v.x + (double)v.y * v.y;
                a1 += (double)v.z * v.z + (double)v.w * v.w;
            }
            nw_s[k] = (float)(a0 + a1);
        }
    }
    if (tid == 0) cnt_s = 0;
    if (tid < TT) { best64[tid] = ~0ull; tmin_s[tid] = 0xFFFFFFFFu; }

    // ---- prologue: quantize x -> K-major token tile + fused fp64 norms ----
    {
        const int t = tid >> 2, q = tid & 3;      // thread: token t, dims q*64..q*64+63
        const float4* xr = (const float4*)(x + (size_t)(tb + t) * DIM + (q << 6));
        double a0 = 0.0, a1 = 0.0;
        #pragma unroll
        for (int i = 0; i < 8; ++i) {
            float4 u = xr[2 * i], v = xr[2 * i + 1];
            *(long*)(ttile + (((q << 3) + i) << 9) + (t << 3)) = pk8(u, v, SX);
            a0 += (double)u.x * u.x + (double)u.y * u.y + (double)v.x * v.x + (double)v.y * v.y;
            a1 += (double)u.z * u.z + (double)u.w * u.w + (double)v.z * v.z + (double)v.w * v.w;
        }
        double nx = a0 + a1;
        nx += __shfl_xor(nx, 1);
        nx += __shfl_xor(nx, 2);
        if (q == 0) nx_s[t] = (float)nx;
    }
    __syncthreads();                              // nw_s + ttile complete

    #pragma unroll
    for (int i = 0; i < 4; ++i) {
        const int k = (i << 8) + tid;
        nwb_s[k] = BIAS_I + (int)rintf(nw_s[k] * (SX * SW * 0.5f));
    }
    __syncthreads();                              // nwb_s complete

    // ---- per-lane top-2 keys per (token-half, quad, chunk-parity): 16-CODE groups
    // (R6/R7-proven granularity: 4 rows x 4 chunks per slot, per h-lane) ----
    unsigned b0[2][8], b1[2][8];
    #pragma unroll
    for (int T = 0; T < 2; ++T)
        #pragma unroll
        for (int s = 0; s < 8; ++s) { b0[T][s] = 0xFFFFFFFFu; b1[T][s] = 0xFFFFFFFFu; }

    // ---- BARRIER-FREE code-streaming loop: wave wv owns codes wv*256..wv*256+255,
    // 8 chunks of 32 codes. A = codes (global/L2, coalesced), B = tokens (LDS). ----
    const int cw = wv << 8;
    long afA[16], afB[16];

    auto LOADF = [&](long* af, int c) {
        const int cbase = cw + (c << 5);
        if (PRE) {
            // K-major workspace: lane = code row; granule 2sp+h at compile-time offsets
            const char* src = (const char*)wqp + (((size_t)(cbase >> 6)) << 14)
                            + (size_t)(((cbase & 63) + ln) << 3) + (size_t)(h << 9);
            #pragma unroll
            for (int sp = 0; sp < 16; ++sp) af[sp] = *(const long*)(src + (sp << 10));
        } else {
            const float4* wrb = (const float4*)(W + (size_t)(cbase + ln) * DIM) + (h << 1);
            #pragma unroll
            for (int sp = 0; sp < 16; ++sp)
                af[sp] = pk8(wrb[sp << 2], wrb[(sp << 2) + 1], SW);
        }
    };

    auto COMPUTE = [&](const long* af, int c) {
        const int cbase = cw + (c << 5);
        const int par = c & 1;                    // compile-time (unrolled caller)
        i32x16 a0v, a1v;
        #pragma unroll
        for (int j = 0; j < 16; ++j) { a0v[j] = 0; a1v[j] = 0; }
        const char* bp = ttile + (h << 9) + (ln << 3);    // conflict-free (R7-verified)
        #pragma unroll
        for (int sp = 0; sp < 16; ++sp) {
            long t0 = *(const long*)(bp + (sp << 10));          // tokens 0..31
            long t1 = *(const long*)(bp + (sp << 10) + 256);    // tokens 32..63
            a0v = __builtin_amdgcn_mfma_i32_32x32x16_i8(af[sp], t0, a0v, 0, 0, 0);
            a1v = __builtin_amdgcn_mfma_i32_32x32x16_i8(af[sp], t1, a1v, 0, 0, 0);
        }
        // integer top-2 update: C row (code) = (j&3)+8*(j>>2)+4h, col (token) = ln
        #pragma unroll
        for (int j = 0; j < 16; ++j) {
            const int kk = cbase + (j & 3) + ((j >> 2) << 3) + (h << 2);
            const int nwb = nwb_s[kk];                    // 32-lane broadcast read
            int c0 = nwb - a0v[j]; c0 = c0 < 0 ? 0 : (c0 > 0x3FFFFF ? 0x3FFFFF : c0);
            int c1 = nwb - a1v[j]; c1 = c1 < 0 ? 0 : (c1 > 0x3FFFFF ? 0x3FFFFF : c1);
            const unsigned u0 = ((unsigned)c0 << 10) | (unsigned)kk;
            const unsigned u1 = ((unsigned)c1 << 10) | (unsigned)kk;
            const int s = ((j >> 2) << 1) | par;          // 16-code group slot
            unsigned lo = umn(u0, b0[0][s]), hi = umx(u0, b0[0][s]);
            b0[0][s] = lo; b1[0][s] = umn(hi, b1[0][s]);
            lo = umn(u1, b0[1][s]); hi = umx(u1, b0[1][s]);
            b0[1][s] = lo; b1[1][s] = umn(hi, b1[1][s]);
        }
    };

    LOADF(afA, 0);
    #pragma unroll
    for (int c = 0; c < 8; c += 2) {              // 1-deep double-buffered prefetch
        LOADF(afB, c + 1);
        COMPUTE(afA, c);
        if (c + 2 < 8) LOADF(afA, c + 2);
        COMPUTE(afB, c + 1);
    }

    // ---- per-token coarse min over this lane's 128 codes; ALL lanes atomicMin ----
    {
        unsigned mn0 = 0xFFFFFFFFu, mn1 = 0xFFFFFFFFu;
        #pragma unroll
        for (int s = 0; s < 8; ++s) {
            mn0 = umn(mn0, b0[0][s]);
            mn1 = umn(mn1, b0[1][s]);
        }
        atomicMin(&tmin_s[ln], mn0);
        atomicMin(&tmin_s[32 + ln], mn1);
    }
    __syncthreads();   // tmin ready; no further ttile reads -> alias as cand list

    // ---- tau-trigger append: per-lane pre-merge top-2 (16-code groups), both h ----
    #pragma unroll
    for (int T = 0; T < 2; ++T) {
        const int t = (T << 5) + ln;
        const unsigned thr = (tmin_s[t] >> 10) + TAU_I;
        #pragma unroll
        for (int s = 0; s < 8; ++s) {
            if ((b0[T][s] >> 10) <= thr) {
                int i = atomicAdd(&cnt_s, 1);
                if (i < CAP) cand[i] = ((unsigned)t << 10) | (b0[T][s] & 1023u);
            }
            if ((b1[T][s] >> 10) <= thr) {
                int i = atomicAdd(&cnt_s, 1);
                if (i < CAP) cand[i] = ((unsigned)t << 10) | (b1[T][s] & 1023u);
            }
        }
    }
    __syncthreads();

    // ---- wave-cooperative exact fp32 rescore; lexicographic (dv,k) atomicMin ----
    const int nc = min(cnt_s, CAP);
    for (int c = wv; c < nc; c += 4) {
        const unsigned en = cand[c];
        const int t = en >> 10, k = en & 1023;
        float4 xv = ((const float4*)(x + (size_t)(tb + t) * DIM))[l];
        float4 wr = ((const float4*)(W + (size_t)k * DIM))[l];
        float s = fmaf(xv.x, wr.x, fmaf(xv.y, wr.y, fmaf(xv.z, wr.z, xv.w * wr.w)));
        #pragma unroll
        for (int m = 1; m <= 32; m <<= 1) s += __shfl_xor(s, m);
        const float dv = (nx_s[t] + nw_s[k]) - 2.0f * s;
        if (l == 0) {
            unsigned long long key = ((unsigned long long)__float_as_uint(dv) << 32) | (unsigned)k;
            atomicMin(&best64[t], key);
        }
    }
    __syncthreads();

    if (tid < TT) {
        const int bk = (int)(best64[tid] & 1023u);
        bk_s[tid] = bk;
        outidx[tb + tid] = (float)bk;
    }
    __syncthreads();

    // ---- gather codebook rows -> quantized output (coalesced float4) ----
    for (int i = tid; i < TT * (DIM / 4); i += 256) {
        const int t = i >> 6, j = i & 63;
        const float4* wr = (const float4*)(W + (size_t)bk_s[t] * DIM);
        ((float4*)(outq + (size_t)(tb + t) * DIM))[j] = wr[j];
    }
}

extern "C" void kernel_launch(void* const* d_in, const int* in_sizes, int n_in,
                              void* d_out, int out_size, void* d_ws, size_t ws_size,
                              hipStream_t stream) {
    const float* x = (const float*)d_in[0];
    const float* W = (const float*)d_in[1];
    float* outq   = (float*)d_out;
    float* outidx = outq + (size_t)NTOK * DIM;

    const size_t need = 4096 + (size_t)NCODE * DIM;   // nw (4KB) + i8 codebook (256KB)
    if (ws_size >= need) {
        float* nw_ws = (float*)d_ws;
        long* wq_ws = (long*)((char*)d_ws + 4096);
        prep_kernel<<<NCODE / 8, 256, 0, stream>>>(W, nw_ws, wq_ws);
        vq_kernel<true><<<NTOK / TT, 256, 0, stream>>>(x, W, nw_ws, wq_ws, outq, outidx);
    } else {
        vq_kernel<false><<<NTOK / TT, 256, 0, stream>>>(x, W, nullptr, nullptr, outq, outidx);
    }
}

// Round 11
// 177.443 us; speedup vs baseline: 1.4422x; 1.4422x over previous
//
#include <hip/hip_runtime.h>
#include <float.h>

typedef int i32x16 __attribute__((ext_vector_type(16)));

#define NTOK   65536
#define DIM    256
#define NCODE  1024
#define TT     64         // tokens per block; grid = 1024
#define CAP    4096
#define SX     20.0f      // x quant scale (clamp at 6.35 sigma)
#define SW     360.0f     // w quant scale (w sigma = 1/16, clamp 5.6 sigma)
#define TAU_I  1260       // 0.35 * SX*SW/2 (int-domain tau; passed R6/R7/R9)
#define BIAS_I 230400     // 64 * SX*SW/2  (keeps int coarse score strictly positive)

__device__ inline unsigned q4(float4 v, float s) {
    int q0 = (int)rintf(fminf(fmaxf(v.x * s, -127.f), 127.f));
    int q1 = (int)rintf(fminf(fmaxf(v.y * s, -127.f), 127.f));
    int q2 = (int)rintf(fminf(fmaxf(v.z * s, -127.f), 127.f));
    int q3 = (int)rintf(fminf(fmaxf(v.w * s, -127.f), 127.f));
    return (unsigned)(q0 & 255) | ((unsigned)(q1 & 255) << 8) |
           ((unsigned)(q2 & 255) << 16) | ((unsigned)(q3 & 255) << 24);
}
__device__ inline long pk8(float4 a, float4 b, float s) {
    union { unsigned u[2]; long l; } r;
    r.u[0] = q4(a, s); r.u[1] = q4(b, s);
    return r.l;
}
__device__ inline unsigned umn(unsigned a, unsigned b) { return a < b ? a : b; }
__device__ inline unsigned umx(unsigned a, unsigned b) { return a > b ? a : b; }

// pre-kernel (R7/R9-verified): ||W_k||^2 fp64->fp32 + W -> i8 K-MAJOR tiles:
// wq[ct*2048 + g*64 + r] = granule g (8 dims) of code row r in 64-code tile ct.
__global__ __launch_bounds__(256) void prep_kernel(const float* __restrict__ W,
                                                   float* __restrict__ nw_out,
                                                   long* __restrict__ wq_out) {
    const int tid = threadIdx.x;
    const int k = blockIdx.x * 8 + (tid >> 5);
    const int c = tid & 31;
    const float4* wr = (const float4*)(W + (size_t)k * DIM + c * 8);
    float4 u = wr[0], v = wr[1];
    wq_out[(size_t)(k >> 6) * 2048 + (size_t)c * 64 + (k & 63)] = pk8(u, v, SW);
    double a = (double)u.x * u.x + (double)u.y * u.y + (double)u.z * u.z + (double)u.w * u.w
             + (double)v.x * v.x + (double)v.y * v.y + (double)v.z * v.z + (double)v.w * v.w;
    #pragma unroll
    for (int m = 1; m <= 16; m <<= 1) a += __shfl_xor(a, m);
    if (c == 0) nw_out[k] = (float)a;
}

// waves_per_eu(2,2): 256-unified-reg window. R9's true pressure ~180 unified regs:
// (256,3) let the allocator pick a 6-wave window (84 regs) -> 186 MB scratch traffic
// (R9). (4,4)=128-window squeezes to 64 and spills (R1/R3). 256-window fits ~180
// with room -> zero spill, 8 waves/CU; the loop is barrier-free so ILP (1-deep
// dbuf) provides the latency hiding instead of TLP.
template <bool PRE>
__global__ __launch_bounds__(256) __attribute__((amdgpu_waves_per_eu(2, 2)))
void vq_kernel(
    const float* __restrict__ x, const float* __restrict__ W,
    const float* __restrict__ nwp, const long* __restrict__ wqp,
    float* __restrict__ outq, float* __restrict__ outidx)
{
    __shared__ __align__(16) char ttile[16384];   // TOKEN tile, K-major: byte = g*512 + t*8
    __shared__ float nw_s[NCODE];                 // fp32 norms (exact rescore)
    __shared__ int   nwb_s[NCODE];                // BIAS_I + rint(nw * SX*SW/2)
    __shared__ float nx_s[TT];
    __shared__ unsigned tmin_s[TT];
    __shared__ unsigned long long best64[TT];
    __shared__ int cnt_s;
    __shared__ int bk_s[TT];
    unsigned* cand = (unsigned*)ttile;            // aliased after coarse phase

    const int tid = threadIdx.x, tb = blockIdx.x * TT;
    const int wv = tid >> 6, l = tid & 63;
    const int ln = l & 31, h = l >> 5;

    // ---- nw: precomputed or fp64 in-block fallback ----
    if (PRE) {
        ((float4*)nw_s)[tid] = ((const float4*)nwp)[tid];
    } else {
        #pragma unroll
        for (int c = 0; c < 4; ++c) {
            const int k = (tid << 2) + c;
            const float4* wr = (const float4*)(W + (size_t)k * DIM);
            double a0 = 0.0, a1 = 0.0;
            for (int q = 0; q < DIM / 4; ++q) {
                float4 v = wr[q];
                a0 += (double)v.x * v.x + (double)v.y * v.y;
                a1 += (double)v.z * v.z + (double)v.w * v.w;
            }
            nw_s[k] = (float)(a0 + a1);
        }
    }
    if (tid == 0) cnt_s = 0;
    if (tid < TT) { best64[tid] = ~0ull; tmin_s[tid] = 0xFFFFFFFFu; }

    // ---- prologue: quantize x -> K-major token tile + fused fp64 norms ----
    {
        const int t = tid >> 2, q = tid & 3;      // thread: token t, dims q*64..q*64+63
        const float4* xr = (const float4*)(x + (size_t)(tb + t) * DIM + (q << 6));
        double a0 = 0.0, a1 = 0.0;
        #pragma unroll
        for (int i = 0; i < 8; ++i) {
            float4 u = xr[2 * i], v = xr[2 * i + 1];
            *(long*)(ttile + (((q << 3) + i) << 9) + (t << 3)) = pk8(u, v, SX);
            a0 += (double)u.x * u.x + (double)u.y * u.y + (double)v.x * v.x + (double)v.y * v.y;
            a1 += (double)u.z * u.z + (double)u.w * u.w + (double)v.z * v.z + (double)v.w * v.w;
        }
        double nx = a0 + a1;
        nx += __shfl_xor(nx, 1);
        nx += __shfl_xor(nx, 2);
        if (q == 0) nx_s[t] = (float)nx;
    }
    __syncthreads();                              // nw_s + ttile complete

    #pragma unroll
    for (int i = 0; i < 4; ++i) {
        const int k = (i << 8) + tid;
        nwb_s[k] = BIAS_I + (int)rintf(nw_s[k] * (SX * SW * 0.5f));
    }
    __syncthreads();                              // nwb_s complete

    // ---- per-lane top-2 keys per (token-half, quad, chunk-parity): 16-CODE groups
    // (R6/R7/R9-proven granularity) ----
    unsigned b0[2][8], b1[2][8];
    #pragma unroll
    for (int T = 0; T < 2; ++T)
        #pragma unroll
        for (int s = 0; s < 8; ++s) { b0[T][s] = 0xFFFFFFFFu; b1[T][s] = 0xFFFFFFFFu; }

    // ---- BARRIER-FREE code-streaming loop: wave wv owns codes wv*256..wv*256+255,
    // 8 chunks of 32 codes. A = codes (global/L2, coalesced), B = tokens (LDS). ----
    const int cw = wv << 8;
    long afA[16], afB[16];

    auto LOADF = [&](long* af, int c) {
        const int cbase = cw + (c << 5);
        if (PRE) {
            // K-major workspace: lane = code row; granule 2sp+h at compile-time offsets
            const char* src = (const char*)wqp + (((size_t)(cbase >> 6)) << 14)
                            + (size_t)(((cbase & 63) + ln) << 3) + (size_t)(h << 9);
            #pragma unroll
            for (int sp = 0; sp < 16; ++sp) af[sp] = *(const long*)(src + (sp << 10));
        } else {
            const float4* wrb = (const float4*)(W + (size_t)(cbase + ln) * DIM) + (h << 1);
            #pragma unroll
            for (int sp = 0; sp < 16; ++sp)
                af[sp] = pk8(wrb[sp << 2], wrb[(sp << 2) + 1], SW);
        }
    };

    auto COMPUTE = [&](const long* af, int c) {
        const int cbase = cw + (c << 5);
        const int par = c & 1;                    // compile-time (unrolled caller)
        i32x16 a0v, a1v;
        #pragma unroll
        for (int j = 0; j < 16; ++j) { a0v[j] = 0; a1v[j] = 0; }
        const char* bp = ttile + (h << 9) + (ln << 3);    // conflict-free (R7-verified)
        #pragma unroll
        for (int sp = 0; sp < 16; ++sp) {
            long t0 = *(const long*)(bp + (sp << 10));          // tokens 0..31
            long t1 = *(const long*)(bp + (sp << 10) + 256);    // tokens 32..63
            a0v = __builtin_amdgcn_mfma_i32_32x32x16_i8(af[sp], t0, a0v, 0, 0, 0);
            a1v = __builtin_amdgcn_mfma_i32_32x32x16_i8(af[sp], t1, a1v, 0, 0, 0);
        }
        // integer top-2 update: C row (code) = (j&3)+8*(j>>2)+4h, col (token) = ln
        #pragma unroll
        for (int j = 0; j < 16; ++j) {
            const int kk = cbase + (j & 3) + ((j >> 2) << 3) + (h << 2);
            const int nwb = nwb_s[kk];                    // 32-lane broadcast read
            int c0 = nwb - a0v[j]; c0 = c0 < 0 ? 0 : (c0 > 0x3FFFFF ? 0x3FFFFF : c0);
            int c1 = nwb - a1v[j]; c1 = c1 < 0 ? 0 : (c1 > 0x3FFFFF ? 0x3FFFFF : c1);
            const unsigned u0 = ((unsigned)c0 << 10) | (unsigned)kk;
            const unsigned u1 = ((unsigned)c1 << 10) | (unsigned)kk;
            const int s = ((j >> 2) << 1) | par;          // 16-code group slot
            unsigned lo = umn(u0, b0[0][s]), hi = umx(u0, b0[0][s]);
            b0[0][s] = lo; b1[0][s] = umn(hi, b1[0][s]);
            lo = umn(u1, b0[1][s]); hi = umx(u1, b0[1][s]);
            b0[1][s] = lo; b1[1][s] = umn(hi, b1[1][s]);
        }
    };

    LOADF(afA, 0);
    #pragma unroll
    for (int c = 0; c < 8; c += 2) {              // 1-deep double-buffered prefetch
        LOADF(afB, c + 1);
        COMPUTE(afA, c);
        if (c + 2 < 8) LOADF(afA, c + 2);
        COMPUTE(afB, c + 1);
    }

    // ---- per-token coarse min over this lane's 128 codes; ALL lanes atomicMin ----
    {
        unsigned mn0 = 0xFFFFFFFFu, mn1 = 0xFFFFFFFFu;
        #pragma unroll
        for (int s = 0; s < 8; ++s) {
            mn0 = umn(mn0, b0[0][s]);
            mn1 = umn(mn1, b0[1][s]);
        }
        atomicMin(&tmin_s[ln], mn0);
        atomicMin(&tmin_s[32 + ln], mn1);
    }
    __syncthreads();   // tmin ready; no further ttile reads -> alias as cand list

    // ---- tau-trigger append: per-lane pre-merge top-2 (16-code groups), both h ----
    #pragma unroll
    for (int T = 0; T < 2; ++T) {
        const int t = (T << 5) + ln;
        const unsigned thr = (tmin_s[t] >> 10) + TAU_I;
        #pragma unroll
        for (int s = 0; s < 8; ++s) {
            if ((b0[T][s] >> 10) <= thr) {
                int i = atomicAdd(&cnt_s, 1);
                if (i < CAP) cand[i] = ((unsigned)t << 10) | (b0[T][s] & 1023u);
            }
            if ((b1[T][s] >> 10) <= thr) {
                int i = atomicAdd(&cnt_s, 1);
                if (i < CAP) cand[i] = ((unsigned)t << 10) | (b1[T][s] & 1023u);
            }
        }
    }
    __syncthreads();

    // ---- wave-cooperative exact fp32 rescore; lexicographic (dv,k) atomicMin ----
    const int nc = min(cnt_s, CAP);
    for (int c = wv; c < nc; c += 4) {
        const unsigned en = cand[c];
        const int t = en >> 10, k = en & 1023;
        float4 xv = ((const float4*)(x + (size_t)(tb + t) * DIM))[l];
        float4 wr = ((const float4*)(W + (size_t)k * DIM))[l];
        float s = fmaf(xv.x, wr.x, fmaf(xv.y, wr.y, fmaf(xv.z, wr.z, xv.w * wr.w)));
        #pragma unroll
        for (int m = 1; m <= 32; m <<= 1) s += __shfl_xor(s, m);
        const float dv = (nx_s[t] + nw_s[k]) - 2.0f * s;
        if (l == 0) {
            unsigned long long key = ((unsigned long long)__float_as_uint(dv) << 32) | (unsigned)k;
            atomicMin(&best64[t], key);
        }
    }
    __syncthreads();

    if (tid < TT) {
        const int bk = (int)(best64[tid] & 1023u);
        bk_s[tid] = bk;
        outidx[tb + tid] = (float)bk;
    }
    __syncthreads();

    // ---- gather codebook rows -> quantized output (coalesced float4) ----
    for (int i = tid; i < TT * (DIM / 4); i += 256) {
        const int t = i >> 6, j = i & 63;
        const float4* wr = (const float4*)(W + (size_t)bk_s[t] * DIM);
        ((float4*)(outq + (size_t)(tb + t) * DIM))[j] = wr[j];
    }
}

extern "C" void kernel_launch(void* const* d_in, const int* in_sizes, int n_in,
                              void* d_out, int out_size, void* d_ws, size_t ws_size,
                              hipStream_t stream) {
    const float* x = (const float*)d_in[0];
    const float* W = (const float*)d_in[1];
    float* outq   = (float*)d_out;
    float* outidx = outq + (size_t)NTOK * DIM;

    const size_t need = 4096 + (size_t)NCODE * DIM;   // nw (4KB) + i8 codebook (256KB)
    if (ws_size >= need) {
        float* nw_ws = (float*)d_ws;
        long* wq_ws = (long*)((char*)d_ws + 4096);
        prep_kernel<<<NCODE / 8, 256, 0, stream>>>(W, nw_ws, wq_ws);
        vq_kernel<true><<<NTOK / TT, 256, 0, stream>>>(x, W, nw_ws, wq_ws, outq, outidx);
    } else {
        vq_kernel<false><<<NTOK / TT, 256, 0, stream>>>(x, W, nullptr, nullptr, outq, outidx);
    }
}